// Round 12
// baseline (101.342 us; speedup 1.0000x reference)
//
#include <hip/hip_runtime.h>
#include <float.h>

// Problem constants (B=16, N=M=4096, fp32, 3-D points)
#define BATCH  16
#define NPTS   4096
#define TOTALP (BATCH * NPTS)      // 65536 points per set
#define NQ     (2 * TOTALP)       // 131072 point slots (both sets)

typedef _Float16 half8  __attribute__((ext_vector_type(8)));
typedef float    f32x16 __attribute__((ext_vector_type(16)));

#define ONE2 0x3C003C00u          // two packed f16 1.0

__device__ __forceinline__ unsigned pk(_Float16 lo, _Float16 hi)
{
    const unsigned a = (unsigned)__builtin_bit_cast(unsigned short, lo);
    const unsigned b = (unsigned)__builtin_bit_cast(unsigned short, hi);
    return a | (b << 16);
}

// In-register min of 16 MFMA outputs + running acc: 8 x v_min3_f32.
__device__ __forceinline__ float min16(const f32x16& d, float acc)
{
    const float m1 = fminf(fminf(d[0],  d[1]),  d[2]);
    const float m2 = fminf(fminf(d[3],  d[4]),  d[5]);
    const float m3 = fminf(fminf(d[6],  d[7]),  d[8]);
    const float m4 = fminf(fminf(d[9],  d[10]), d[11]);
    const float m5 = fminf(fminf(d[12], d[13]), d[14]);
    const float m6 = fminf(fminf(m1, m2), m3);
    const float m7 = fminf(fminf(m4, m5), d[15]);
    return fminf(fminf(m6, m7), acc);
}

// ---------------------------------------------------------------------------
// Prep kernel (512 blocks x 256): for every point i of both sets, write
//   packQ[i]   query record (u = -2x), minimal 16 B; B-frag halves are
//              {d.x,d.y,d.z,d.x} / {d.y,d.z,d.w,1|1} -> zero shuffling
//   planes[0][i] / planes[1][i]  opp record pre-expanded in MFMA A-frag
//              K-half layout -> main kernel streams them coalesced, no LDS
// Also zeroes out[0..1] (poisoned 0xAA; main accumulates with atomicAdd).
// One K=16 f16 dot of (A-rec, B-rec) = ||x - p||^2 exactly (R8-R11 absmax=0).
// ---------------------------------------------------------------------------
__global__ __launch_bounds__(256) void prep_kernel(
    const float* __restrict__ xyz1, const float* __restrict__ xyz2,
    uint4* __restrict__ packQ, uint4* __restrict__ planes,
    float* __restrict__ out)
{
    const int i = blockIdx.x * 256 + threadIdx.x;    // 0..131071
    if (i == 0) { out[0] = 0.0f; out[1] = 0.0f; }

    const float* src = (i < TOTALP) ? xyz1 : xyz2;
    const int p = i & (TOTALP - 1);
    const float x = src[3 * p + 0];
    const float y = src[3 * p + 1];
    const float z = src[3 * p + 2];
    const float sq = x * x + y * y + z * z;
    const _Float16 sh = (_Float16)sq;
    const _Float16 sl = (_Float16)(sq - (float)sh);

    // Opp-role A-fragment halves (v = x):
    //   half0 k0-7:  vxh vyh vzh vxh vyh vzh vxl vyl
    //   half1 k8-15: vzl vxl vyl vzl 1 1 sh sl
    const _Float16 vxh = (_Float16)x, vyh = (_Float16)y, vzh = (_Float16)z;
    const _Float16 vxl = (_Float16)(x - (float)vxh);
    const _Float16 vyl = (_Float16)(y - (float)vyh);
    const _Float16 vzl = (_Float16)(z - (float)vzh);
    planes[i]      = make_uint4(pk(vxh, vyh), pk(vzh, vxh),
                                pk(vyh, vzh), pk(vxl, vyl));
    planes[NQ + i] = make_uint4(pk(vzl, vxl), pk(vyl, vzl),
                                ONE2,         pk(sh, sl));

    // Query-role record (u = -2x), minimal:
    const float ux = -2.0f * x, uy = -2.0f * y, uz = -2.0f * z;
    const _Float16 uxh = (_Float16)ux, uyh = (_Float16)uy, uzh = (_Float16)uz;
    const _Float16 uxl = (_Float16)(ux - (float)uxh);
    const _Float16 uyl = (_Float16)(uy - (float)uyh);
    const _Float16 uzl = (_Float16)(uz - (float)uzh);
    packQ[i] = make_uint4(pk(uxh, uyh), pk(uzh, uxl), pk(uyl, uzl), pk(sh, sl));
}

// ---------------------------------------------------------------------------
// Fused MFMA chamfer: ONE kernel completes each query's min over the whole
// opposite set -> no keys array, no merge kernel.
//   blk = (dir*16 + b)*32 + qc      (ALL selectors block-uniform)
//   Block: 128 queries (4 waves x 32) x ALL 4096 opp points (128 tiles).
//   Grid: 2 x 16 x 32 = 1024 blocks -> 4 blocks/CU.
// Per wave: ONE B-frag (4 VGPRs) of 32 queries held in registers; opp stream
// is coalesced global b128 with depth-2 prefetch and TWO independent dd
// chains (even/odd tiles) so MFMA-latency of one chain overlaps the other
// chain's min16 (breaks the WAR serialization suspected in R10/R11).
// D layout: col(query)=lane&31, row(opp)->16 regs => min16 is in-register;
// shfl_xor(32) merges row-halves; butterfly(16..1) sums each 32-lane group's
// query mins; one atomicAdd per block into out[dir]. No LDS in the hot path.
// ---------------------------------------------------------------------------
__global__ __launch_bounds__(256) void chamfer_fused(
    const uint4* __restrict__ packQ, const uint4* __restrict__ planes,
    float* __restrict__ out)
{
    const int blk = blockIdx.x;
    const int qc  = blk & 31;
    const int b   = (blk >> 5) & 15;
    const int dir = blk >> 9;                    // block-uniform

    const int lane = threadIdx.x & 63;
    const int wv   = threadIdx.x >> 6;
    const int n32  = lane & 31;
    const int half = lane >> 5;

    // ---- wave's 32 queries: one B-fragment, zero-shuffle assembly ----
    const int qbase = dir * TOTALP + b * NPTS + qc * 128 + wv * 32;
    const uint4 d = packQ[qbase + n32];
    const uint4 u = half ? make_uint4(d.y, d.z, d.w, ONE2)
                         : make_uint4(d.x, d.y, d.z, d.x);
    const half8 bfrag = __builtin_bit_cast(half8, u);

    f32x16 cz;
#pragma unroll
    for (int r = 0; r < 16; ++r) cz[r] = 0.0f;

    // ---- opp stream: 128 tiles of 32 recs, coalesced b128, prefetch 2 ----
    const uint4* __restrict__ ap =
        planes + (size_t)half * NQ + (dir ^ 1) * TOTALP + b * NPTS;

    float acc0 = FLT_MAX, acc1 = FLT_MAX;
    uint4 c0 = ap[0 * 32 + n32];
    uint4 c1 = ap[1 * 32 + n32];

    for (int t = 0; t < 128; t += 2) {
        const uint4 n0 = ap[(((t + 2) & 127) * 32) + n32];
        const uint4 n1 = ap[(((t + 3) & 127) * 32) + n32];
        const f32x16 d0 = __builtin_amdgcn_mfma_f32_32x32x16_f16(
            __builtin_bit_cast(half8, c0), bfrag, cz, 0, 0, 0);
        const f32x16 d1 = __builtin_amdgcn_mfma_f32_32x32x16_f16(
            __builtin_bit_cast(half8, c1), bfrag, cz, 0, 0, 0);
        acc0 = min16(d0, acc0);                  // chain 0
        acc1 = min16(d1, acc1);                  // chain 1 (independent)
        c0 = n0; c1 = n1;
    }

    // ---- epilogue ----
    float v = fminf(acc0, acc1);
    v = fminf(v, __shfl_xor(v, 32));   // merge row-halves: full query min
    // butterfly sum of the 32 query-mins within each 32-lane group
    v += __shfl_xor(v, 16);
    v += __shfl_xor(v, 8);
    v += __shfl_xor(v, 4);
    v += __shfl_xor(v, 2);
    v += __shfl_xor(v, 1);
    __shared__ float wsum[4];
    if (lane == 0) wsum[wv] = v;
    __syncthreads();
    if (threadIdx.x == 0) {
        const float s = wsum[0] + wsum[1] + wsum[2] + wsum[3];
        atomicAdd(&out[dir], s * (1.0f / (float)TOTALP));
    }
}

// ---------------------------------------------------------------------------
// Fallback for tiny workspace: direct 7-op kernel, no ws needed.
// ---------------------------------------------------------------------------
__global__ void zero_out_kernel(float* __restrict__ out)
{
    if (threadIdx.x == 0) { out[0] = 0.0f; out[1] = 0.0f; }
}

__global__ __launch_bounds__(256) void chamfer_raw_kernel(
    const float* __restrict__ xyz1, const float* __restrict__ xyz2,
    float* __restrict__ out)
{
    const int blk = blockIdx.x;
    const int dir = blk >> 8;
    const int idx = blk & 255;
    const int b   = idx >> 4;
    const int n0  = (idx & 15) << 8;

    const float* __restrict__ own = (dir == 0 ? xyz1 : xyz2) + (size_t)b * NPTS * 3;
    const float* __restrict__ opp = (dir == 0 ? xyz2 : xyz1) + (size_t)b * NPTS * 3;

    const int n = n0 + threadIdx.x;
    const float ax = own[3 * n + 0];
    const float ay = own[3 * n + 1];
    const float az = own[3 * n + 2];

    float best = FLT_MAX;
    for (int m = 0; m < NPTS; m += 4) {
#pragma unroll
        for (int u = 0; u < 4; ++u) {
            const float px = opp[3 * (m + u) + 0];
            const float py = opp[3 * (m + u) + 1];
            const float pz = opp[3 * (m + u) + 2];
            const float dx = px - ax, dy = py - ay, dz = pz - az;
            float d = dx * dx;
            d = fmaf(dy, dy, d);
            d = fmaf(dz, dz, d);
            best = fminf(best, d);
        }
    }

    float d = best;
    for (int off = 32; off > 0; off >>= 1)
        d += __shfl_down(d, off);

    __shared__ float wsum[4];
    const int lane = threadIdx.x & 63;
    const int wv   = threadIdx.x >> 6;
    if (lane == 0) wsum[wv] = d;
    __syncthreads();
    if (threadIdx.x == 0) {
        float s = wsum[0] + wsum[1] + wsum[2] + wsum[3];
        atomicAdd(&out[dir], s * (1.0f / (float)TOTALP));
    }
}

// ---------------------------------------------------------------------------
extern "C" void kernel_launch(void* const* d_in, const int* in_sizes, int n_in,
                              void* d_out, int out_size, void* d_ws, size_t ws_size,
                              hipStream_t stream)
{
    const float* xyz1 = (const float*)d_in[0];
    const float* xyz2 = (const float*)d_in[1];
    float* out = (float*)d_out;

    const size_t packQ_bytes = (size_t)NQ * sizeof(uint4);      // 2 MiB
    const size_t plane_bytes = (size_t)2 * NQ * sizeof(uint4);  // 4 MiB

    if (ws_size >= packQ_bytes + plane_bytes) {                 // 6 MiB
        uint4* packQ  = (uint4*)d_ws;
        uint4* planes = (uint4*)((char*)d_ws + packQ_bytes);

        prep_kernel<<<NQ / 256, 256, 0, stream>>>(xyz1, xyz2, packQ, planes, out);
        // 1024 blocks: dir(2) x b(16) x qc(32) -> 4 blocks/CU
        chamfer_fused<<<1024, 256, 0, stream>>>(packQ, planes, out);
    } else {
        zero_out_kernel<<<1, 64, 0, stream>>>(out);
        chamfer_raw_kernel<<<512, 256, 0, stream>>>(xyz1, xyz2, out);
    }
}